// Round 1
// baseline (239.052 us; speedup 1.0000x reference)
//
#include <hip/hip_runtime.h>

// Problem constants
#define NPOS    65536      // B*D*H*W = 4*16*32*32
#define CDIM    64         // C
#define KCODES  1024       // codebook size
#define NCHUNK  4          // K split factor
#define KCHUNK  256        // KCODES / NCHUNK
#define SPATIAL 16384      // D*H*W
#define QELEMS  4194304    // B*C*D*H*W

// Workspace layout (float index units)
#define NORM_OFF   0
#define PSCORE_OFF 1024
#define PIDX_OFF   (1024 + NPOS * NCHUNK)
#define LOSS_OFF   (1024 + 2 * NPOS * NCHUNK)

__global__ void k_norms(const float* __restrict__ emb, float* __restrict__ wsf) {
    int k = blockIdx.x * blockDim.x + threadIdx.x;
    if (k == 0) wsf[LOSS_OFF] = 0.0f;
    if (k < KCODES) {
        const float4* e4 = (const float4*)(emb + (size_t)k * CDIM);
        float s = 0.0f;
#pragma unroll
        for (int c = 0; c < CDIM / 4; ++c) {
            float4 e = e4[c];
            s += e.x * e.x + e.y * e.y + e.z * e.z + e.w * e.w;
        }
        wsf[NORM_OFF + k] = s;
    }
}

__global__ __launch_bounds__(256, 4) void k_search(const float* __restrict__ z_e,
                                                   const float* __restrict__ emb,
                                                   float* __restrict__ wsf) {
    const int bp  = blockIdx.x >> 2;   // position block
    const int bk  = blockIdx.x & 3;    // K chunk (block-uniform -> scalar loads)
    const int n   = bp * 256 + threadIdx.x;
    const int b   = n >> 14;           // / SPATIAL
    const int dhw = n & (SPATIAL - 1);

    // Load this position's C=64 vector into registers (coalesced across lanes per c)
    const float* zb = z_e + ((size_t)b * CDIM) * SPATIAL + dhw;
    float x[CDIM];
#pragma unroll
    for (int c = 0; c < CDIM; ++c) x[c] = zb[(size_t)c * SPATIAL];

    const int   kbase = bk * KCHUNK;
    const float* __restrict__ ep = emb + (size_t)kbase * CDIM;
    const float* __restrict__ nrm = wsf + NORM_OFF + kbase;

    float best = 3.4e38f;
    int   bidx = kbase;
    for (int k = 0; k < KCHUNK; ++k) {
        const float4* e4 = (const float4*)(ep + (size_t)k * CDIM);
        float s0 = 0.f, s1 = 0.f, s2 = 0.f, s3 = 0.f;
#pragma unroll
        for (int c = 0; c < CDIM / 4; ++c) {
            float4 e = e4[c];
            s0 = fmaf(x[4 * c + 0], e.x, s0);
            s1 = fmaf(x[4 * c + 1], e.y, s1);
            s2 = fmaf(x[4 * c + 2], e.z, s2);
            s3 = fmaf(x[4 * c + 3], e.w, s3);
        }
        float dot   = (s0 + s1) + (s2 + s3);
        float score = fmaf(-2.0f, dot, nrm[k]);
        if (score < best) { best = score; bidx = kbase + k; }
    }
    wsf[PSCORE_OFF + bk * NPOS + n]          = best;
    ((int*)wsf)[PIDX_OFF + bk * NPOS + n]    = bidx;
}

__global__ void k_finalize(const float* __restrict__ z_e,
                           const float* __restrict__ emb,
                           float* __restrict__ out,
                           float* __restrict__ wsf) {
    const int n   = blockIdx.x * 256 + threadIdx.x;
    const int b   = n >> 14;
    const int dhw = n & (SPATIAL - 1);

    // Merge the NCHUNK partial argmins (ascending chunk + strict < keeps first min)
    float best = wsf[PSCORE_OFF + n];
    int   bidx = ((const int*)wsf)[PIDX_OFF + n];
#pragma unroll
    for (int ch = 1; ch < NCHUNK; ++ch) {
        float s = wsf[PSCORE_OFF + ch * NPOS + n];
        int   i = ((const int*)wsf)[PIDX_OFF + ch * NPOS + n];
        if (s < best) { best = s; bidx = i; }
    }

    // indices output (as float, matching f32 output buffer)
    out[QELEMS + 2 + n] = (float)bidx;

    const float*  zb = z_e + ((size_t)b * CDIM) * SPATIAL + dhw;
    float*        qb = out + ((size_t)b * CDIM) * SPATIAL + dhw;
    const float4* e4 = (const float4*)(emb + (size_t)bidx * CDIM);

    float lsum = 0.0f;
#pragma unroll
    for (int c4 = 0; c4 < CDIM / 4; ++c4) {
        float4 ev = e4[c4];
        float  evs[4] = {ev.x, ev.y, ev.z, ev.w};
#pragma unroll
        for (int j = 0; j < 4; ++j) {
            int   c  = 4 * c4 + j;
            float xv = zb[(size_t)c * SPATIAL];
            float d  = evs[j] - xv;              // quantized - z_e (f32 rounding)
            qb[(size_t)c * SPATIAL] = xv + d;    // straight-through arithmetic
            lsum = fmaf(d, d, lsum);
        }
    }

    // wave-level reduction then one atomic per wave
#pragma unroll
    for (int off = 32; off > 0; off >>= 1) lsum += __shfl_down(lsum, off);
    if ((threadIdx.x & 63) == 0) atomicAdd(&wsf[LOSS_OFF], lsum);
}

__global__ void k_loss(const float* __restrict__ wsf, float* __restrict__ out) {
    float m = wsf[LOSS_OFF] / (float)QELEMS;
    out[QELEMS]     = m;  // codebook_loss
    out[QELEMS + 1] = m;  // commitment_loss (same forward value)
}

extern "C" void kernel_launch(void* const* d_in, const int* in_sizes, int n_in,
                              void* d_out, int out_size, void* d_ws, size_t ws_size,
                              hipStream_t stream) {
    const float* z_e = (const float*)d_in[0];
    const float* emb = (const float*)d_in[1];
    float*       out = (float*)d_out;
    float*       wsf = (float*)d_ws;

    k_norms<<<KCODES / 256, 256, 0, stream>>>(emb, wsf);
    k_search<<<(NPOS / 256) * NCHUNK, 256, 0, stream>>>(z_e, emb, wsf);
    k_finalize<<<NPOS / 256, 256, 0, stream>>>(z_e, emb, out, wsf);
    k_loss<<<1, 1, 0, stream>>>(wsf, out);
}

// Round 5
// 238.093 us; speedup vs baseline: 1.0040x; 1.0040x over previous
//
#include <hip/hip_runtime.h>

// Problem constants
#define NPOS    65536      // B*D*H*W = 4*16*32*32
#define CDIM    64         // C
#define KCODES  1024       // codebook size
#define NCHUNK  8          // K split factor
#define KCHUNK  128        // KCODES / NCHUNK
#define SPATIAL 16384      // D*H*W
#define QELEMS  4194304    // B*C*D*H*W

// Workspace layout:
//   u64 wsu[NPOS]      : packed (mono_score<<10 | idx) per position, atomicMin target
//   float at index 131072 (byte 524288): loss accumulator
#define LOSSF_IDX 131072

__global__ __launch_bounds__(256, 6) void k_search(const float* __restrict__ z_e,
                                                   const float* __restrict__ emb,
                                                   unsigned long long* __restrict__ wsu,
                                                   float* __restrict__ wsf) {
    __shared__ float nrm[KCHUNK];
    const int bp    = blockIdx.x >> 3;   // position block
    const int bk    = blockIdx.x & 7;    // K chunk (block-uniform -> scalar loads)
    const int kbase = bk * KCHUNK;

    // Block-local codebook norms into LDS (threads 0..127, one code each)
    if (threadIdx.x < KCHUNK) {
        const float4* e4 = (const float4*)(emb + (size_t)(kbase + threadIdx.x) * CDIM);
        float s = 0.0f;
#pragma unroll
        for (int c = 0; c < CDIM / 4; ++c) {
            float4 e = e4[c];
            s += e.x * e.x + e.y * e.y + e.z * e.z + e.w * e.w;
        }
        nrm[threadIdx.x] = s;
    }
    if (blockIdx.x == 0 && threadIdx.x == 0) wsf[LOSSF_IDX] = 0.0f;  // before k_finalize's atomics
    __syncthreads();

    const int n   = bp * 256 + threadIdx.x;
    const int b   = n >> 14;           // / SPATIAL
    const int dhw = n & (SPATIAL - 1);

    // This position's C=64 vector in registers (coalesced across lanes per c)
    const float* zb = z_e + (size_t)b * (CDIM * SPATIAL) + dhw;
    float x[CDIM];
#pragma unroll
    for (int c = 0; c < CDIM; ++c) x[c] = zb[(size_t)c * SPATIAL];

    const float* __restrict__ ep = emb + (size_t)kbase * CDIM;

    float best = 3.4e38f;
    int   bidx = 0;
#pragma unroll 2
    for (int k = 0; k < KCHUNK; ++k) {
        const float4* e4 = (const float4*)(ep + (size_t)k * CDIM);
        float s0 = 0.f, s1 = 0.f, s2 = 0.f, s3 = 0.f;
#pragma unroll
        for (int c = 0; c < CDIM / 4; ++c) {
            float4 e = e4[c];
            s0 = fmaf(x[4 * c + 0], e.x, s0);
            s1 = fmaf(x[4 * c + 1], e.y, s1);
            s2 = fmaf(x[4 * c + 2], e.z, s2);
            s3 = fmaf(x[4 * c + 3], e.w, s3);
        }
        float dot   = (s0 + s1) + (s2 + s3);
        float score = fmaf(-2.0f, dot, nrm[k]);
        if (score < best) { best = score; bidx = k; }   // strict < : first-min within chunk
    }

    // Pack: monotonic f32 bits (score-major) | idx (minor, 10 bits).
    // Global atomicMin == argmin with first-occurrence tie-break (lower idx wins ties).
    unsigned u    = __float_as_uint(best);
    unsigned mono = (u & 0x80000000u) ? ~u : (u | 0x80000000u);
    unsigned long long packed = ((unsigned long long)mono << 10) | (unsigned)(kbase + bidx);
    atomicMin(&wsu[n], packed);
}

__global__ void k_finalize(const float* __restrict__ z_e,
                           const float* __restrict__ emb,
                           float* __restrict__ out,
                           const unsigned long long* __restrict__ wsu,
                           float* __restrict__ wsf) {
    const int n    = blockIdx.x * 256 + threadIdx.x;
    const int b    = n >> 14;
    const int dhw  = n & (SPATIAL - 1);
    const int bidx = (int)(wsu[n] & 1023ull);

    out[QELEMS + 2 + n] = (float)bidx;   // indices output (f32 buffer)

    const float*  zb = z_e + (size_t)b * (CDIM * SPATIAL) + dhw;
    float*        qb = out + (size_t)b * (CDIM * SPATIAL) + dhw;
    const float4* e4 = (const float4*)(emb + (size_t)bidx * CDIM);

    float lsum = 0.0f;
#pragma unroll
    for (int c4 = 0; c4 < CDIM / 4; ++c4) {
        float4 ev = e4[c4];
        float  evs[4] = {ev.x, ev.y, ev.z, ev.w};
#pragma unroll
        for (int j = 0; j < 4; ++j) {
            int   c  = 4 * c4 + j;
            float xv = zb[(size_t)c * SPATIAL];
            float d  = evs[j] - xv;              // quantized - z_e (f32 rounding)
            qb[(size_t)c * SPATIAL] = xv + d;    // straight-through arithmetic
            lsum = fmaf(d, d, lsum);
        }
    }

    // wave-level reduction then one atomic per wave
#pragma unroll
    for (int off = 32; off > 0; off >>= 1) lsum += __shfl_down(lsum, off);
    if ((threadIdx.x & 63) == 0) atomicAdd(&wsf[LOSSF_IDX], lsum);
}

__global__ void k_loss(const float* __restrict__ wsf, float* __restrict__ out) {
    float m = wsf[LOSSF_IDX] / (float)QELEMS;
    out[QELEMS]     = m;  // codebook_loss
    out[QELEMS + 1] = m;  // commitment_loss (same forward value)
}

extern "C" void kernel_launch(void* const* d_in, const int* in_sizes, int n_in,
                              void* d_out, int out_size, void* d_ws, size_t ws_size,
                              hipStream_t stream) {
    const float* z_e = (const float*)d_in[0];
    const float* emb = (const float*)d_in[1];
    float*       out = (float*)d_out;
    unsigned long long* wsu = (unsigned long long*)d_ws;
    float*       wsf = (float*)d_ws;

    // Init packed slots to 0xFF.. (>= any packed value; harness poison 0xAA also works,
    // but the first correctness call's ws state is unspecified -> explicit init).
    hipMemsetAsync(d_ws, 0xFF, (size_t)NPOS * 8, stream);

    k_search<<<(NPOS / 256) * NCHUNK, 256, 0, stream>>>(z_e, emb, wsu, wsf);
    k_finalize<<<NPOS / 256, 256, 0, stream>>>(z_e, emb, out, wsu, wsf);
    k_loss<<<1, 1, 0, stream>>>(wsf, out);
}